// Round 1
// baseline (142.536 us; speedup 1.0000x reference)
//
#include <hip/hip_runtime.h>
#include <math.h>

#define BB   8
#define HH   384
#define WW   384
#define NN   96
#define HWSZ (HH * WW)
#define NSEG (NN - 1)
#define SEGF 12            // floats per segment record
#define DMAXV 15.0f

// ---------------------------------------------------------------------------
// Kernel 1: 7x7 cross-correlation (SAME, zero pad) of pred and |pred| with the
// 2-channel Gaussian-edge filter, scaled by EXTGRADFAC=10.
// g[b][c][y][x], gw[b][c][y][x]
// ---------------------------------------------------------------------------
__global__ __launch_bounds__(256) void conv_kernel(
    const float* __restrict__ pred, const float* __restrict__ fltr,
    float* __restrict__ g, float* __restrict__ gw)
{
    __shared__ float sf[98];  // [2][49]
    int tid = threadIdx.x;
    if (tid < 98) sf[tid] = fltr[tid];
    __syncthreads();

    int gidx = blockIdx.x * 256 + tid;     // 0 .. B*HW-1 (exact grid)
    int b = gidx / HWSZ;
    int p = gidx - b * HWSZ;
    int y = p / WW;
    int x = p - y * WW;
    const float* pb = pred + b * HWSZ;

    float a0 = 0.f, a1 = 0.f, a2 = 0.f, a3 = 0.f;
#pragma unroll
    for (int ky = 0; ky < 7; ++ky) {
        int iy = y + ky - 3;
        bool oky = (iy >= 0) && (iy < HH);
        const float* row = pb + iy * WW;
#pragma unroll
        for (int kx = 0; kx < 7; ++kx) {
            int ix = x + kx - 3;
            float v = (oky && ix >= 0 && ix < WW) ? row[ix] : 0.0f;
            float f0 = sf[ky * 7 + kx];
            float f1 = sf[49 + ky * 7 + kx];
            float av = fabsf(v);
            a0 = fmaf(v,  f0, a0);
            a1 = fmaf(v,  f1, a1);
            a2 = fmaf(av, f0, a2);
            a3 = fmaf(av, f1, a3);
        }
    }
    float* gb  = g  + b * 2 * HWSZ;
    float* gwb = gw + b * 2 * HWSZ;
    gb[p]         = a0 * 10.0f;
    gb[HWSZ + p]  = a1 * 10.0f;
    gwb[p]        = a2 * 10.0f;
    gwb[HWSZ + p] = a3 * 10.0f;
}

// bilinear sample of a 2-channel image (channel stride HWSZ), ref-identical
__device__ inline void bilin2(const float* __restrict__ img, float py, float px,
                              float& v0, float& v1)
{
    float y = fminf(fmaxf(py, 0.0f), (float)(HH - 1));
    float x = fminf(fmaxf(px, 0.0f), (float)(WW - 1));
    int y0 = (int)floorf(y);
    int x0 = (int)floorf(x);
    int y1 = min(y0 + 1, HH - 1);
    int x1 = min(x0 + 1, WW - 1);
    float wy = y - (float)y0;
    float wx = x - (float)x0;
    float w00 = (1.f - wy) * (1.f - wx);
    float w01 = (1.f - wy) * wx;
    float w10 = wy * (1.f - wx);
    float w11 = wy * wx;
    const float* c0 = img;
    const float* c1 = img + HWSZ;
    int i00 = y0 * WW + x0, i01 = y0 * WW + x1, i10 = y1 * WW + x0, i11 = y1 * WW + x1;
    v0 = c0[i00] * w00 + c0[i01] * w01 + c0[i10] * w10 + c0[i11] * w11;
    v1 = c1[i00] * w00 + c1[i01] * w01 + c1[i10] * w10 + c1[i11] * w11;
}

// ---------------------------------------------------------------------------
// Kernel 2: snake evolution (50 position steps + 10 width steps) per sample.
// One block per sample, thread i handles node i. Emits per-segment records:
// [ay, ax, aby, abx, aab, denom, inv_denom, aa, ws, ylo, yhi, pad]
// ---------------------------------------------------------------------------
__global__ __launch_bounds__(128) void snake_kernel(
    const float* __restrict__ nodes, const float* __restrict__ widths,
    const float* __restrict__ g, const float* __restrict__ gw,
    float* __restrict__ segs)
{
    __shared__ float sx[2][2][NN];   // [buf][coord y/x][node]
    __shared__ float sd2[2][NN];
    __shared__ float swd[NN];

    int b = blockIdx.x;
    int i = threadIdx.x;
    const float* gb  = g  + b * 2 * HWSZ;
    const float* gwb = gw + b * 2 * HWSZ;

    float xy = 0.f, xx = 0.f;
    if (i < NN) {
        xy = nodes[(b * NN + i) * 2 + 0];
        xx = nodes[(b * NN + i) * 2 + 1];
        sx[0][0][i] = xy;
        sx[0][1][i] = xx;
    }
    __syncthreads();

    int il = (i > 0) ? i - 1 : 0;
    int ir = (i < NN - 1) ? i + 1 : NN - 1;
    int cur = 0;

    for (int s = 0; s < 50; ++s) {
        float d2y = 0.f, d2x = 0.f;
        if (i < NN) {
            d2y = sx[cur][0][il] - 2.0f * xy + sx[cur][0][ir];
            d2x = sx[cur][1][il] - 2.0f * xx + sx[cur][1][ir];
            sd2[0][i] = d2y;
            sd2[1][i] = d2x;
        }
        __syncthreads();
        if (i < NN) {
            float d4y = sd2[0][il] - 2.0f * d2y + sd2[0][ir];
            float d4x = sd2[1][il] - 2.0f * d2x + sd2[1][ir];
            float f0, f1;
            bilin2(gb, xy, xx, f0, f1);
            xy = xy + 0.1f * (0.01f * d2y - 0.01f * d4y + f0);
            xx = xx + 0.1f * (0.01f * d2x - 0.01f * d4x + f1);
            sx[1 - cur][0][i] = xy;
            sx[1 - cur][1][i] = xx;
        }
        __syncthreads();
        cur = 1 - cur;
    }

    // tangent / outward normal
    float ny = 0.f, nx = 0.f;
    if (i < NN) {
        float ty, tx;
        if (i == 0)           { ty = sx[cur][0][1] - xy;            tx = sx[cur][1][1] - xx; }
        else if (i == NN - 1) { ty = xy - sx[cur][0][NN - 2];       tx = xx - sx[cur][1][NN - 2]; }
        else                  { ty = 0.5f * (sx[cur][0][i + 1] - sx[cur][0][i - 1]);
                                tx = 0.5f * (sx[cur][1][i + 1] - sx[cur][1][i - 1]); }
        float n0 = -tx, n1 = ty;
        float nrm = sqrtf(n0 * n0 + n1 * n1) + 1e-6f;
        ny = n0 / nrm;
        nx = n1 / nrm;
    }

    float w = 0.f;
    if (i < NN) w = widths[b * NN + i];
    for (int s = 0; s < 10; ++s) {
        if (i < NN) {
            float p0, p1, m0, m1;
            bilin2(gwb, xy + w * ny, xx + w * nx, p0, p1);
            bilin2(gwb, xy - w * ny, xx - w * nx, m0, m1);
            float f = 0.5f * ((p0 * ny + p1 * nx) - (m0 * ny + m1 * nx));
            w = fmaxf(w + 0.1f * f, 0.5f);
        }
    }
    if (i < NN) swd[i] = w;
    __syncthreads();

    if (i < NSEG) {
        float by = sx[cur][0][i + 1], bx = sx[cur][1][i + 1];
        float aby = by - xy, abx = bx - xx;
        float denom = aby * aby + abx * abx + 1e-8f;
        float aab = xy * aby + xx * abx;
        float aa  = xy * xy + xx * xx;
        float wseg = 0.5f * (w + swd[i + 1]);
        float ymin = fminf(xy, by), ymax = fmaxf(xy, by);
        float reach = DMAXV + wseg;
        float* r = segs + (b * NSEG + i) * SEGF;
        r[0]  = xy;   r[1]  = xx;
        r[2]  = aby;  r[3]  = abx;
        r[4]  = aab;  r[5]  = denom;
        r[6]  = 1.0f / denom;
        r[7]  = aa;   r[8]  = wseg;
        r[9]  = ymin - reach;
        r[10] = ymax + reach;
        r[11] = 0.f;
    }
}

// ---------------------------------------------------------------------------
// Kernel 3: render distance map row-by-row + MSE partial sums.
// One block per (b, row). Row y is block-uniform -> a uniform [lo,hi] segment
// window prunes ~95 -> ~12 segments with zero divergence.
// ---------------------------------------------------------------------------
__global__ __launch_bounds__(384) void render_kernel(
    const float* __restrict__ pred, const float* __restrict__ segs,
    float* __restrict__ partials)
{
    __shared__ float ss[NSEG * SEGF];
    __shared__ int slo, shi;
    __shared__ float swsum[6];

    int b = blockIdx.x / HH;
    int y = blockIdx.x - b * HH;
    int t = threadIdx.x;          // pixel x (0..383)

    const float* sb = segs + b * NSEG * SEGF;
    for (int j = t; j < NSEG * SEGF; j += 384) ss[j] = sb[j];
    if (t == 0) { slo = NSEG; shi = -1; }
    __syncthreads();

    float py = (float)y;
    if (t < NSEG) {
        float ylo = ss[t * SEGF + 9];
        float yhi = ss[t * SEGF + 10];
        if (py >= ylo && py <= yhi) {
            atomicMin(&slo, t);
            atomicMax(&shi, t);
        }
    }
    __syncthreads();

    float px = (float)t;
    float pp = py * py + px * px;
    float minv = DMAXV;

    int lo = slo, hi = shi;
    for (int si = lo; si <= hi; ++si) {
        const float* r = ss + si * SEGF;
        float dotpa = fmaf(py, r[2], fmaf(px, r[3], -r[4]));
        float tt = fminf(fmaxf(dotpa * r[6], 0.0f), 1.0f);
        float pa2 = fmaf(py, -2.0f * r[0], fmaf(px, -2.0f * r[1], pp + r[7]));
        float d2 = fmaf(tt, fmaf(tt, r[5], -2.0f * dotpa), pa2);
        float d = sqrtf(fmaxf(d2, 0.0f));
        float v = fmaxf(d - r[8], 0.0f);
        minv = fminf(minv, v);
    }

    float pr = pred[b * HWSZ + y * WW + t];
    float diff = pr - minv;
    float sq = diff * diff;

    // block reduction: 6 waves of 64
#pragma unroll
    for (int off = 32; off > 0; off >>= 1) sq += __shfl_down(sq, off, 64);
    if ((t & 63) == 0) swsum[t >> 6] = sq;
    __syncthreads();
    if (t == 0) {
        float tot = swsum[0] + swsum[1] + swsum[2] + swsum[3] + swsum[4] + swsum[5];
        partials[blockIdx.x] = tot;
    }
}

// ---------------------------------------------------------------------------
// Kernel 4: reduce 3072 partials -> mean -> d_out[0]
// ---------------------------------------------------------------------------
__global__ __launch_bounds__(1024) void finalize_kernel(
    const float* __restrict__ partials, float* __restrict__ out)
{
    __shared__ float sred[16];
    int t = threadIdx.x;
    float s = 0.f;
    for (int j = t; j < BB * HH; j += 1024) s += partials[j];
#pragma unroll
    for (int off = 32; off > 0; off >>= 1) s += __shfl_down(s, off, 64);
    if ((t & 63) == 0) sred[t >> 6] = s;
    __syncthreads();
    if (t == 0) {
        float tot = 0.f;
        for (int k = 0; k < 16; ++k) tot += sred[k];
        out[0] = tot * (1.0f / (float)(BB * HWSZ));
    }
}

extern "C" void kernel_launch(void* const* d_in, const int* in_sizes, int n_in,
                              void* d_out, int out_size, void* d_ws, size_t ws_size,
                              hipStream_t stream)
{
    const float* pred   = (const float*)d_in[0];   // (8,1,384,384)
    const float* nodes  = (const float*)d_in[1];   // (8,96,2)
    const float* widths = (const float*)d_in[2];   // (8,96)
    const float* fltr   = (const float*)d_in[3];   // (2,1,7,7)
    float* out = (float*)d_out;

    float* ws       = (float*)d_ws;
    float* g        = ws;                          // B*2*HW
    float* gw       = g  + (size_t)BB * 2 * HWSZ;  // B*2*HW
    float* segs     = gw + (size_t)BB * 2 * HWSZ;  // B*95*12
    float* partials = segs + (size_t)BB * NSEG * SEGF; // B*H

    conv_kernel<<<(BB * HWSZ) / 256, 256, 0, stream>>>(pred, fltr, g, gw);
    snake_kernel<<<BB, 128, 0, stream>>>(nodes, widths, g, gw, segs);
    render_kernel<<<BB * HH, 384, 0, stream>>>(pred, segs, partials);
    finalize_kernel<<<1, 1024, 0, stream>>>(partials, out);
}